// Round 17
// baseline (615.333 us; speedup 1.0000x reference)
//
#include <hip/hip_runtime.h>
#include <math.h>

// ---------------------------------------------------------------------------
// MultiReferenceWindowAttention — bf16-MFMA GEMMs (128x192 tile, balanced
// DS:MFMA, pure-copy staging, coalesced bf16 epilogue, head-blocked kk/vv)
// + t-merged window attention.
// B_=128, T=4, M=4, N=64, C=192, nH=6, hd=32, BT=512
// Workspace map unchanged (peak 176.75 MB <= 177,340,416 B proven).
//
// VGPR/SPILL MODEL (settled): hipcc's VGPR target follows launch_bounds
// min-waves (cap ~= 512/min_waves); it SPILLS rather than exceed. Keep live
// state under the cap. winattn(768,1): 84 live, no spill. mgemm(256,2):
// acc[4][6]=96 + frags ~40 -> ~150 live < 256 cap.
// r16 lesson: 128x96-tile GEMM was DS-read-bound (7 ds_read : 12 MFMA).
// r17: 128x192 tile, wave 64x96 -> 10 ds_read : 24 MFMA (balanced).
// winattn is DS-pipe-bound (structural for f32-LDS) — parked at ~170 us.
// ---------------------------------------------------------------------------

typedef float f32x4 __attribute__((ext_vector_type(4)));
typedef short s16x8 __attribute__((ext_vector_type(8)));
typedef unsigned short u16x4 __attribute__((ext_vector_type(4)));
typedef unsigned short u16x8 __attribute__((ext_vector_type(8)));

__device__ __forceinline__ unsigned short f2bf(float f) {
    union { float f; unsigned u; } c; c.f = f;
    return (unsigned short)((c.u + 0x7fffu + ((c.u >> 16) & 1u)) >> 16);
}
__device__ __forceinline__ float bf2f(unsigned short h) {
    union { unsigned u; float f; } c; c.u = ((unsigned)h) << 16;
    return c.f;
}

// ---- all 7 weights -> packed bf16 (element offsets: q 0, kv 36864,
// pq 110592, pk 147456, pv 184320, po 221184, proj 258048; total 294912)
__global__ void wcvt_kernel(const float* __restrict__ q_w, const float* __restrict__ kv_w,
                            const float* __restrict__ pq_w, const float* __restrict__ pk_w,
                            const float* __restrict__ pv_w, const float* __restrict__ po_w,
                            const float* __restrict__ proj_w, unsigned short* __restrict__ wbf)
{
    int i = blockIdx.x * 256 + threadIdx.x;
    if (i >= 294912) return;
    const float* src; int off;
    if      (i < 36864)  { src = q_w;    off = 0; }
    else if (i < 110592) { src = kv_w;   off = 36864; }
    else if (i < 147456) { src = pq_w;   off = 110592; }
    else if (i < 184320) { src = pk_w;   off = 147456; }
    else if (i < 221184) { src = pv_w;   off = 184320; }
    else if (i < 258048) { src = po_w;   off = 221184; }
    else                 { src = proj_w; off = 258048; }
    wbf[i] = f2bf(src[i - off]);
}

// ---- prep: t0b = mean_m(xp2)  (xp2 already includes pos, added in winattn)
__global__ void prep_kernel(const unsigned short* __restrict__ xp,
                            unsigned short* __restrict__ t0b)
{
    int i = blockIdx.x * 256 + threadIdx.x;   // 786432 total
    int c8 = (i % 24) * 8;
    int n  = (i / 24) & 63;
    int bt = i / (24 * 64);
    float acc[8] = {0, 0, 0, 0, 0, 0, 0, 0};
    size_t base = (size_t)bt * 49152 + n * 192 + c8;
#pragma unroll
    for (int m = 0; m < 4; m++) {
        u16x8 v = *reinterpret_cast<const u16x8*>(&xp[base + m * 12288]);
#pragma unroll
        for (int e = 0; e < 8; e++) acc[e] += bf2f(v[e]);
    }
    u16x8 t;
#pragma unroll
    for (int e = 0; e < 8; e++) t[e] = f2bf(acc[e] * 0.25f);
    *reinterpret_cast<u16x8*>(&t0b[(size_t)(bt * 64 + n) * 192 + c8]) = t;
}

// ---------------------------------------------------------------------------
// MFMA bf16 GEMM v2:  C[row, oc] = sum_k Arow[k] * W[oc][k] + bias[oc]
// Block tile 128 rows x 192 oc; 4 waves in 2x2, wave tile 64x96 (acc[4][6]).
// K=192 staged in 2 halves of 96. LDS: As 24KB + Bs 36KB = 60KB.
// grid.y is 192-aligned: for split outputs (EPI 2/3) a whole block is C0 or C1.
// SRC: 0 = A f32 rows (cvt); 3 = Ab bf16 row-major (pure copy);
//      4 = seq rows: g -> (bt=c0+g/320, tok); tok<64 -> Ab2(t0b) else Ab(xp2).
// EPI: 0 plain, 1 exact gelu, 2 split (b0 len 384), 3 split (W1,b1).
// OUTBF: 0 f32 out; 1 bf16 out via LDS restage -> coalesced u16x8 stores.
// hbs: 0 row-major out; else head-blocked [h][row][32], h-stride hbs elems.
// ---------------------------------------------------------------------------
template <int SRC, int EPI, int OUTBF>
__global__ __launch_bounds__(256, 2)
void mgemm_kernel(const float* __restrict__ A, const unsigned short* __restrict__ Ab,
                  const unsigned short* __restrict__ Ab2,
                  const unsigned short* __restrict__ W0, const unsigned short* __restrict__ W1,
                  const float* __restrict__ b0, const float* __restrict__ b1,
                  void* __restrict__ C0v, void* __restrict__ C1v, int c0, int hbs)
{
    __shared__ __align__(16) char smem[61440];     // As 24KB | Bs 36KB
    char* As = smem;
    char* Bs = smem + 24576;
    const int tid = threadIdx.x;
    const int gm0 = blockIdx.x * 128;
    const int gn0 = blockIdx.y * 192;
    const int wid = tid >> 6;
    const int wm = wid >> 1, wn = wid & 1;
    const int lane = tid & 63;
    const int lr = lane & 15;
    const int lk = lane >> 4;

    const bool hiN = (gn0 >= 192);
    const unsigned short* Wsel = (EPI == 3 && hiN) ? W1 : W0;
    const int wrow0 = (EPI == 3 && hiN) ? 0 : gn0;

    f32x4 acc[4][6];
#pragma unroll
    for (int i = 0; i < 4; i++)
#pragma unroll
        for (int j = 0; j < 6; j++) acc[i][j] = (f32x4){0.f, 0.f, 0.f, 0.f};

    for (int kb = 0; kb < 192; kb += 96) {
        // ---- stage A: 128 rows x 96 k ----
        if (SRC == 0) {
#pragma unroll
            for (int it = 0; it < 12; it++) {
                int f4 = tid + it * 256;
                int row = f4 / 24;
                int kc4 = (f4 - row * 24) * 4;
                float4 v = *reinterpret_cast<const float4*>(
                    &A[(size_t)(gm0 + row) * 192 + kb + kc4]);
                u16x4 bvv;
                bvv[0] = f2bf(v.x); bvv[1] = f2bf(v.y);
                bvv[2] = f2bf(v.z); bvv[3] = f2bf(v.w);
                int boff = (kc4 * 2) ^ ((row & 3) << 4);
                *reinterpret_cast<u16x4*>(As + row * 192 + boff) = bvv;
            }
        } else {
#pragma unroll
            for (int it = 0; it < 6; it++) {
                int f8 = tid + it * 256;
                int row = f8 / 12;
                int c16 = f8 - row * 12;
                const unsigned short* src;
                if (SRC == 3) {
                    src = &Ab[(size_t)(gm0 + row) * 192 + kb + c16 * 8];
                } else {
                    int g = gm0 + row;
                    int bt = g / 320, tok = g - bt * 320; bt += c0;
                    src = (tok < 64)
                        ? &Ab2[(size_t)(bt * 64 + tok) * 192 + kb + c16 * 8]
                        : &Ab[(size_t)bt * 49152 + ((tok >> 6) - 1) * 12288
                              + (tok & 63) * 192 + kb + c16 * 8];
                }
                u16x8 v = *reinterpret_cast<const u16x8*>(src);
                int boff = (c16 * 16) ^ ((row & 3) << 4);
                *reinterpret_cast<u16x8*>(As + row * 192 + boff) = v;
            }
        }
        // ---- stage B: 192 oc-rows x 96 k, pure bf16 copy (9 per thread) ----
        for (int f8 = tid; f8 < 2304; f8 += 256) {
            int row = f8 / 12;
            int c16 = f8 - row * 12;
            u16x8 v = *reinterpret_cast<const u16x8*>(
                &Wsel[(size_t)(wrow0 + row) * 192 + kb + c16 * 8]);
            int boff = (c16 * 16) ^ ((row & 3) << 4);
            *reinterpret_cast<u16x8*>(Bs + row * 192 + boff) = v;
        }
        __syncthreads();

#pragma unroll
        for (int ks = 0; ks < 3; ks++) {
            s16x8 af[4], bf[6];
#pragma unroll
            for (int i = 0; i < 4; i++) {
                int row = wm * 64 + i * 16 + lr;
                int off = (ks * 64 + lk * 16) ^ ((row & 3) << 4);
                af[i] = *reinterpret_cast<const s16x8*>(As + row * 192 + off);
            }
#pragma unroll
            for (int j = 0; j < 6; j++) {
                int row = wn * 96 + j * 16 + lr;
                int off = (ks * 64 + lk * 16) ^ ((row & 3) << 4);
                bf[j] = *reinterpret_cast<const s16x8*>(Bs + row * 192 + off);
            }
#pragma unroll
            for (int i = 0; i < 4; i++)
#pragma unroll
                for (int j = 0; j < 6; j++)
                    acc[i][j] = __builtin_amdgcn_mfma_f32_16x16x32_bf16(
                        af[i], bf[j], acc[i][j], 0, 0, 0);
        }
        __syncthreads();
    }

    const bool toC1 = ((EPI == 2 || EPI == 3) && hiN);
    if (OUTBF == 0) {
#pragma unroll
        for (int j = 0; j < 6; j++) {
            int loc = wn * 96 + j * 16 + lr;            // 0..191 local col
            float bv = (EPI == 3 && hiN) ? b1[loc] : b0[gn0 + loc];
            float* dst = (float*)(toC1 ? C1v : C0v);
#pragma unroll
            for (int i = 0; i < 4; i++) {
                int rbase = gm0 + wm * 64 + i * 16 + lk * 4;
#pragma unroll
                for (int r = 0; r < 4; r++) {
                    float v = acc[i][j][r] + bv;
                    if (EPI == 1) v = 0.5f * v * (1.f + erff(v * 0.70710678118654752440f));
                    dst[(size_t)(rbase + r) * 192 + loc] = v;
                }
            }
        }
    } else {
        // bf16 out: restage via smem (128*192 u16 = 48KB <= 60KB), coalesced
        unsigned short* As16 = (unsigned short*)smem;
#pragma unroll
        for (int j = 0; j < 6; j++) {
            int loc = wn * 96 + j * 16 + lr;
            float bv = (EPI == 3 && hiN) ? b1[loc] : b0[gn0 + loc];
#pragma unroll
            for (int i = 0; i < 4; i++)
#pragma unroll
                for (int r = 0; r < 4; r++) {
                    float v = acc[i][j][r] + bv;
                    if (EPI == 1) v = 0.5f * v * (1.f + erff(v * 0.70710678118654752440f));
                    As16[(wm * 64 + i * 16 + lk * 4 + r) * 192 + loc] = f2bf(v);
                }
        }
        __syncthreads();
        unsigned short* dst = (unsigned short*)(toC1 ? C1v : C0v);
#pragma unroll
        for (int it = 0; it < 12; it++) {
            int f8 = tid + it * 256;                    // 0..3071
            int row = f8 / 24, c16 = f8 - row * 24;
            u16x8 v = *reinterpret_cast<const u16x8*>(&As16[row * 192 + c16 * 8]);
            size_t idx;
            int col = c16 * 8;                          // 8-chunk stays in a head
            if (hbs == 0) {
                idx = (size_t)(gm0 + row) * 192 + col;
            } else {
                idx = (size_t)(col >> 5) * (size_t)hbs
                    + (size_t)(gm0 + row) * 32 + (col & 31);
            }
            *reinterpret_cast<u16x8*>(&dst[idx]) = v;
        }
    }
}

// ---------------------------------------------------------------------------
// Fused window attention, t-MERGED (r15 proven): block = (bb, m), 512 blocks,
// 768 thr = 12 waves; K/V/mask/rpbT staged F32 once, t=0..3 looped inside.
// VGPR 84, zero spill. Epilogue adds pos before bf16 rounding.
// ---------------------------------------------------------------------------
__global__ __launch_bounds__(768, 1)
void winattn_kernel(const float* __restrict__ qbuf,
                    const unsigned short* __restrict__ kbuf,
                    const unsigned short* __restrict__ vbuf,
                    const float* __restrict__ mask,
                    const float* __restrict__ rpbt, const float* __restrict__ pos,
                    unsigned short* __restrict__ xp)
{
    __shared__ float klds[64 * 192];       // 48 KB
    __shared__ float vlds[64 * 192];       // 48 KB
    __shared__ float mlds[64 * 65];        // 16.25 KB
    __shared__ float rldsT[6 * 225];       // 5.3 KB  [h][ridx]
    __shared__ float exm[768];
    __shared__ float exl[768];
    __shared__ unsigned obuf[6 * 64 * 17]; // 25.5 KB
    const int tid = threadIdx.x;
    const int bid = blockIdx.x;            // bb*4 + m
    const int bb = bid >> 2;
    const int m = bid & 3;
    const int w = tid >> 6;
    const int h = w >> 1;
    const int lane = tid & 63;

    const int kvbase = (bb * 4 + m) * 12288;
#pragma unroll
    for (int it = 0; it < 2; it++) {
        int i8 = tid + it * 768;
        u16x8 kq = *reinterpret_cast<const u16x8*>(&kbuf[kvbase + i8 * 8]);
        u16x8 vq = *reinterpret_cast<const u16x8*>(&vbuf[kvbase + i8 * 8]);
        f32x4 k0, k1, v0, v1;
#pragma unroll
        for (int e = 0; e < 4; e++) {
            k0[e] = bf2f(kq[e]); k1[e] = bf2f(kq[e + 4]);
            v0[e] = bf2f(vq[e]); v1[e] = bf2f(vq[e + 4]);
        }
        *reinterpret_cast<f32x4*>(&klds[i8 * 8]) = k0;
        *reinterpret_cast<f32x4*>(&klds[i8 * 8 + 4]) = k1;
        *reinterpret_cast<f32x4*>(&vlds[i8 * 8]) = v0;
        *reinterpret_cast<f32x4*>(&vlds[i8 * 8 + 4]) = v1;
    }
    const int widx = bb & 63;
    for (int f = tid; f < 4096; f += 768)
        mlds[(f >> 6) * 65 + (f & 63)] = mask[widx * 4096 + f];
    for (int f = tid; f < 1350; f += 768) {
        int hh = f / 225, rr = f - hh * 225;
        rldsT[f] = rpbt[rr * 6 + hh];
    }
    __syncthreads();

    const float scale = 0.17677669529663688110f;  // 1/sqrt(32)
    const int ni = lane >> 3, nj = lane & 7;
    const int e0 = (w & 1) << 5;

    for (int t = 0; t < 4; t++) {
        float qreg[32];
        const int qbase = ((bb * 4 + t) * 64 + lane) * 192 + h * 32;
#pragma unroll
        for (int j = 0; j < 8; j++) {
            float4 v = *reinterpret_cast<const float4*>(&qbuf[qbase + j * 4]);
            qreg[4 * j] = v.x; qreg[4 * j + 1] = v.y;
            qreg[4 * j + 2] = v.z; qreg[4 * j + 3] = v.w;
        }
        float s[32];
#pragma unroll
        for (int ee = 0; ee < 32; ee++) {
            int e = e0 + ee;
            const float4* kr = reinterpret_cast<const float4*>(&klds[e * 192 + h * 32]);
            float d0 = 0, d1 = 0, d2 = 0, d3 = 0;
#pragma unroll
            for (int q8 = 0; q8 < 8; q8++) {
                float4 k4 = kr[q8];
                d0 += qreg[q8 * 4] * k4.x;
                d1 += qreg[q8 * 4 + 1] * k4.y;
                d2 += qreg[q8 * 4 + 2] * k4.z;
                d3 += qreg[q8 * 4 + 3] * k4.w;
            }
            int ridx = (ni - (e >> 3) + 7) * 15 + (nj - (e & 7) + 7);
            s[ee] = (d0 + d1 + d2 + d3) * scale + rldsT[h * 225 + ridx] + mlds[lane * 65 + e];
        }
        float mrun = s[0];
#pragma unroll
        for (int ee = 1; ee < 32; ee++) mrun = fmaxf(mrun, s[ee]);
        float lrun = 0.f;
#pragma unroll
        for (int ee = 0; ee < 32; ee++) { s[ee] = __expf(s[ee] - mrun); lrun += s[ee]; }

        float o[32];
#pragma unroll
        for (int d = 0; d < 32; d++) o[d] = 0.f;
#pragma unroll
        for (int ee = 0; ee < 32; ee++) {
            float p = s[ee];
            const float4* vr = reinterpret_cast<const float4*>(&vlds[(e0 + ee) * 192 + h * 32]);
#pragma unroll
            for (int d8 = 0; d8 < 8; d8++) {
                float4 v4 = vr[d8];
                o[d8 * 4] += p * v4.x; o[d8 * 4 + 1] += p * v4.y;
                o[d8 * 4 + 2] += p * v4.z; o[d8 * 4 + 3] += p * v4.w;
            }
        }

        __syncthreads();                   // B1: prior t's obuf/exl reads done
        exm[w * 64 + lane] = mrun;
        __syncthreads();                   // B2
        float mo = exm[(w ^ 1) * 64 + lane];
        float mt = fmaxf(mrun, mo);
        float fs = __expf(mrun - mt);
        if (w & 1) {
            unsigned* ob = &obuf[h * 1088 + lane * 17];
#pragma unroll
            for (int j = 0; j < 16; j++) {
                unsigned lo = f2bf(fs * o[2 * j]);
                unsigned hi = f2bf(fs * o[2 * j + 1]);
                ob[j] = lo | (hi << 16);
            }
            exl[w * 64 + lane] = fs * lrun;
        }
        __syncthreads();                   // B3
        if (!(w & 1)) {
            float lt = fs * lrun + exl[(w + 1) * 64 + lane];
            const float inv = 1.f / lt;
            const unsigned* ob = &obuf[h * 1088 + lane * 17];
            const int obase = bb * 196608 + m * 49152 + t * 12288 + h * 2048 + lane * 32;
#pragma unroll
            for (int j = 0; j < 8; j++) {
                unsigned p0 = ob[2 * j], p1 = ob[2 * j + 1];
                float4 pv = *reinterpret_cast<const float4*>(&pos[h * 2048 + lane * 32 + j * 4]);
                u16x4 v;
                v[0] = f2bf((fs * o[4 * j]     + bf2f((unsigned short)(p0 & 0xffff))) * inv + pv.x);
                v[1] = f2bf((fs * o[4 * j + 1] + bf2f((unsigned short)(p0 >> 16))) * inv + pv.y);
                v[2] = f2bf((fs * o[4 * j + 2] + bf2f((unsigned short)(p1 & 0xffff))) * inv + pv.z);
                v[3] = f2bf((fs * o[4 * j + 3] + bf2f((unsigned short)(p1 >> 16))) * inv + pv.w);
                *reinterpret_cast<u16x4*>(&xp[obase + j * 4]) = v;
            }
        }
    }
}

// ---------------------------------------------------------------------------
// Pooling attention (r16 proven): block = (h, btl), 320 thr = 5 waves;
// head-blocked kk/vv, qreg reloaded per key-tile, 4-wave merge.
// ---------------------------------------------------------------------------
__global__ __launch_bounds__(320)
void poolattn3_kernel(const unsigned short* __restrict__ kk,
                      const unsigned short* __restrict__ vv,
                      const float* __restrict__ qq,
                      unsigned short* __restrict__ opool, int c0, int hbs)
{
    __shared__ float ubuf[10560];
    __shared__ float scm[320], scl[320];
    const int tid = threadIdx.x;
    const int w = tid >> 6, lane = tid & 63;
    const int h = blockIdx.x, btl = blockIdx.y;
    const int bt = c0 + btl;
    float* Kf = ubuf + w * 2048;
    float* Vf = Kf + 1024;

    const float scale = 0.17677669529663688110f;
    float mrun = -3.0e38f, lrun = 0.f;
    float o[32];
#pragma unroll
    for (int d = 0; d < 32; d++) o[d] = 0.f;

    const size_t qbase = (size_t)(bt * 64 + lane) * 192 + h * 32;
    const size_t hb = (size_t)h * hbs;

#pragma unroll 1
    for (int it = 0; it < 2; it++) {
        const int tt = w + it * 5;
        const unsigned short* ks = kk + hb + ((size_t)btl * 320 + tt * 32) * 32;
        const unsigned short* vs = vv + hb + ((size_t)btl * 320 + tt * 32) * 32;
#pragma unroll
        for (int ci = 0; ci < 2; ci++) {
            int i8 = lane + ci * 64;
            u16x8 kv8 = *reinterpret_cast<const u16x8*>(&ks[i8 * 8]);
            u16x8 vv8 = *reinterpret_cast<const u16x8*>(&vs[i8 * 8]);
            f32x4 lo, hi, vlo, vhi;
#pragma unroll
            for (int e = 0; e < 4; e++) {
                lo[e] = bf2f(kv8[e]);  hi[e] = bf2f(kv8[e + 4]);
                vlo[e] = bf2f(vv8[e]); vhi[e] = bf2f(vv8[e + 4]);
            }
            *reinterpret_cast<f32x4*>(Kf + i8 * 8) = lo;
            *reinterpret_cast<f32x4*>(Kf + i8 * 8 + 4) = hi;
            *reinterpret_cast<f32x4*>(Vf + i8 * 8) = vlo;
            *reinterpret_cast<f32x4*>(Vf + i8 * 8 + 4) = vhi;
        }
        float qreg[32];
#pragma unroll
        for (int j = 0; j < 8; j++) {
            float4 v = *reinterpret_cast<const float4*>(&qq[qbase + j * 4]);
            qreg[4 * j] = v.x; qreg[4 * j + 1] = v.y;
            qreg[4 * j + 2] = v.z; qreg[4 * j + 3] = v.w;
        }
        float s[32];
#pragma unroll
        for (int j = 0; j < 32; j++) {
            const float4* kr = reinterpret_cast<const float4*>(Kf + j * 32);
            float d0 = 0, d1 = 0, d2 = 0, d3 = 0;
#pragma unroll
            for (int q8 = 0; q8 < 8; q8++) {
                float4 k4 = kr[q8];
                d0 += qreg[q8 * 4] * k4.x;
                d1 += qreg[q8 * 4 + 1] * k4.y;
                d2 += qreg[q8 * 4 + 2] * k4.z;
                d3 += qreg[q8 * 4 + 3] * k4.w;
            }
            s[j] = (d0 + d1 + d2 + d3) * scale;
        }
        float mt = s[0];
#pragma unroll
        for (int j = 1; j < 32; j++) mt = fmaxf(mt, s[j]);
        float mnew = fmaxf(mrun, mt);
        float fct = __expf(mrun - mnew);
        lrun *= fct;
#pragma unroll
        for (int d = 0; d < 32; d++) o[d] *= fct;
#pragma unroll
        for (int j = 0; j < 32; j++) { float p = __expf(s[j] - mnew); lrun += p; s[j] = p; }
#pragma unroll
        for (int j = 0; j < 32; j++) {
            float p = s[j];
            const float4* vr = reinterpret_cast<const float4*>(Vf + j * 32);
#pragma unroll
            for (int d8 = 0; d8 < 8; d8++) {
                float4 v4 = vr[d8];
                o[d8 * 4] += p * v4.x; o[d8 * 4 + 1] += p * v4.y;
                o[d8 * 4 + 2] += p * v4.z; o[d8 * 4 + 3] += p * v4.w;
            }
        }
        mrun = mnew;
    }
    __syncthreads();
    scm[w * 64 + lane] = mrun;
    scl[w * 64 + lane] = lrun;
#pragma unroll
    for (int d = 0; d < 32; d++) ubuf[w * 2112 + lane * 33 + d] = o[d];
    __syncthreads();

    if (tid < 256) {                 // 4-wave merge: q = tid&63, 8 dims each
        const int q = tid & 63, grp = tid >> 6;
        float m5 = scm[q];
#pragma unroll
        for (int ww = 1; ww < 5; ww++) m5 = fmaxf(m5, scm[ww * 64 + q]);
        float den = 0.f;
        float od[8];
#pragma unroll
        for (int e = 0; e < 8; e++) od[e] = 0.f;
#pragma unroll
        for (int ww = 0; ww < 5; ww++) {
            float f = __expf(scm[ww * 64 + q] - m5);
            den += f * scl[ww * 64 + q];
            const float* src = ubuf + ww * 2112 + q * 33 + grp * 8;
#pragma unroll
            for (int e = 0; e < 8; e++) od[e] += f * src[e];
        }
        const float inv = 1.f / den;
        const size_t ob = (size_t)(bt * 64 + q) * 192 + h * 32 + grp * 8;
        u16x4 v0, v1;
#pragma unroll
        for (int e = 0; e < 4; e++) { v0[e] = f2bf(od[e] * inv); v1[e] = f2bf(od[e + 4] * inv); }
        *reinterpret_cast<u16x4*>(&opool[ob]) = v0;
        *reinterpret_cast<u16x4*>(&opool[ob + 4]) = v1;
    }
}

extern "C" void kernel_launch(void* const* d_in, const int* in_sizes, int n_in,
                              void* d_out, int out_size, void* d_ws, size_t ws_size,
                              hipStream_t stream) {
    (void)in_sizes; (void)n_in; (void)out_size; (void)ws_size;
    const float* x      = (const float*)d_in[0];
    const float* x_kv   = (const float*)d_in[1];
    const float* mask   = (const float*)d_in[2];
    const float* rpbt   = (const float*)d_in[3];
    const float* q_w    = (const float*)d_in[4];
    const float* q_b    = (const float*)d_in[5];
    const float* kv_w   = (const float*)d_in[6];
    const float* kv_b   = (const float*)d_in[7];
    const float* pos    = (const float*)d_in[8];
    const float* pq_w   = (const float*)d_in[9];
    const float* pq_b   = (const float*)d_in[10];
    const float* pk_w   = (const float*)d_in[11];
    const float* pk_b   = (const float*)d_in[12];
    const float* pv_w   = (const float*)d_in[13];
    const float* pv_b   = (const float*)d_in[14];
    const float* po_w   = (const float*)d_in[15];
    const float* po_b   = (const float*)d_in[16];
    const float* proj_w = (const float*)d_in[17];
    const float* proj_b = (const float*)d_in[18];
    float* out = (float*)d_out;
    char* ws = (char*)d_ws;

    float*          qbuf   = (float*)(ws);                        // 24 MB
    unsigned short* xp     = (unsigned short*)(ws + 25165824u);   // 48 MB
    unsigned short* kbuf   = (unsigned short*)(ws + 75497472u);   // 12 MB
    unsigned short* vbuf   = (unsigned short*)(ws + 88080384u);   // 12 MB
    unsigned short* kkc    = (unsigned short*)(ws + 75497472u);   // 30 MB/chunk
    unsigned short* vvc    = (unsigned short*)(ws + 106954752u);  // 30 MB/chunk
    unsigned short* t0b    = (unsigned short*)(ws + 138412032u);  // 12.6 MB
    unsigned short* opoolb = (unsigned short*)(ws + 150994944u);  // 12.6 MB
    unsigned short* opob   = (unsigned short*)(ws + 163577856u);  // 12.6 MB
    unsigned short* wbf    = (unsigned short*)(ws + 176160768u);  // 0.59 MB
    float*          qq     = qbuf;
    const int HBS = 256 * 320 * 32;   // head-block stride (elements) per chunk

    dim3 blk(256);
    wcvt_kernel<<<1152, blk, 0, stream>>>(q_w, kv_w, pq_w, pk_w, pv_w, po_w, proj_w, wbf);
    // q = x @ q_w^T + q_b  (f32 A path)
    mgemm_kernel<0, 0, 0><<<dim3(256, 1), blk, 0, stream>>>(
        x, nullptr, nullptr, wbf, nullptr, q_b, nullptr, qbuf, nullptr, 0, 0);
    // k,v = x_kv @ kv_w^T + kv_b  (split per-block, bf16 out)
    mgemm_kernel<0, 2, 1><<<dim3(256, 2), blk, 0, stream>>>(
        x_kv, nullptr, nullptr, wbf + 36864, nullptr, kv_b, nullptr, kbuf, vbuf, 0, 0);
    // window attention, t-merged; writes xp2 = attn_out + pos
    winattn_kernel<<<512, 768, 0, stream>>>(qbuf, kbuf, vbuf, mask, rpbt, pos, xp);
    // t0 = mean_m(xp2)
    prep_kernel<<<3072, blk, 0, stream>>>(xp, t0b);
    // qq = t0 @ pq_w^T + pq_b
    mgemm_kernel<3, 0, 0><<<dim3(256, 1), blk, 0, stream>>>(
        nullptr, t0b, nullptr, wbf + 110592, nullptr, pq_b, nullptr, qq, nullptr, 0, 0);
    // pooling in 2 chunks of 256 bt (kk/vv head-blocked)
    for (int c0 = 0; c0 < 512; c0 += 256) {
        mgemm_kernel<4, 3, 1><<<dim3(640, 2), blk, 0, stream>>>(
            nullptr, xp, t0b, wbf + 147456, wbf + 184320, pk_b, pv_b, kkc, vvc, c0, HBS);
        poolattn3_kernel<<<dim3(6, 256), 320, 0, stream>>>(kkc, vvc, qq, opoolb, c0, HBS);
    }
    // opo = gelu(opool @ po_w^T + po_b)  (bf16 in/out)
    mgemm_kernel<3, 1, 1><<<dim3(256, 1), blk, 0, stream>>>(
        nullptr, opoolb, nullptr, wbf + 221184, nullptr, po_b, nullptr, opob, nullptr, 0, 0);
    // out = opo @ proj_w^T + proj_b  (f32 out)
    mgemm_kernel<3, 0, 0><<<dim3(256, 1), blk, 0, stream>>>(
        nullptr, opob, nullptr, wbf + 258048, nullptr, proj_b, nullptr, out, nullptr, 0, 0);
}

// Round 18
// 600.958 us; speedup vs baseline: 1.0239x; 1.0239x over previous
//
#include <hip/hip_runtime.h>
#include <math.h>

// ---------------------------------------------------------------------------
// MultiReferenceWindowAttention — bf16-MFMA GEMMs (pure-copy staging,
// coalesced bf16 epilogue, head-blocked kk/vv) + t-merged window attention.
// B_=128, T=4, M=4, N=64, C=192, nH=6, hd=32, BT=512
// Workspace map unchanged from r14/r15, peak 176.75 MB (<= 177,340,416 B).
//
// VGPR/SPILL MODEL (settled r7..r15): hipcc targets ~84 VGPR for 768-thread
// blocks (and similar for 320-thread) and SPILLS rather than exceed. The rule
// is LIVE STATE <= ~84: winattn t-loop keeps per-t state transient (84, no
// spill). poolattn3 reloads qreg per iteration (#pragma unroll 1 defeats
// CSE-hoisting) so cross-phase live ~ 40.
// winattn is DS-pipe-bound (8 ds_read_b128 : 32 FMA per key) — parked.
// r17 lesson: 128x192 GEMM tile regressed (fewer blocks -> lost 2-block/CU
// overlap); 128x96 tile with (256,3) launch_bounds is the proven optimum.
// ---------------------------------------------------------------------------

typedef float f32x4 __attribute__((ext_vector_type(4)));
typedef short s16x8 __attribute__((ext_vector_type(8)));
typedef unsigned short u16x4 __attribute__((ext_vector_type(4)));
typedef unsigned short u16x8 __attribute__((ext_vector_type(8)));

__device__ __forceinline__ unsigned short f2bf(float f) {
    union { float f; unsigned u; } c; c.f = f;
    return (unsigned short)((c.u + 0x7fffu + ((c.u >> 16) & 1u)) >> 16);
}
__device__ __forceinline__ float bf2f(unsigned short h) {
    union { unsigned u; float f; } c; c.u = ((unsigned)h) << 16;
    return c.f;
}

// ---- all 7 weights -> packed bf16 (element offsets: q 0, kv 36864,
// pq 110592, pk 147456, pv 184320, po 221184, proj 258048; total 294912)
__global__ void wcvt_kernel(const float* __restrict__ q_w, const float* __restrict__ kv_w,
                            const float* __restrict__ pq_w, const float* __restrict__ pk_w,
                            const float* __restrict__ pv_w, const float* __restrict__ po_w,
                            const float* __restrict__ proj_w, unsigned short* __restrict__ wbf)
{
    int i = blockIdx.x * 256 + threadIdx.x;
    if (i >= 294912) return;
    const float* src; int off;
    if      (i < 36864)  { src = q_w;    off = 0; }
    else if (i < 110592) { src = kv_w;   off = 36864; }
    else if (i < 147456) { src = pq_w;   off = 110592; }
    else if (i < 184320) { src = pk_w;   off = 147456; }
    else if (i < 221184) { src = pv_w;   off = 184320; }
    else if (i < 258048) { src = po_w;   off = 221184; }
    else                 { src = proj_w; off = 258048; }
    wbf[i] = f2bf(src[i - off]);
}

// ---- prep: t0b = mean_m(xp2)  (xp2 already includes pos, added in winattn)
__global__ void prep_kernel(const unsigned short* __restrict__ xp,
                            unsigned short* __restrict__ t0b)
{
    int i = blockIdx.x * 256 + threadIdx.x;   // 786432 total
    int c8 = (i % 24) * 8;
    int n  = (i / 24) & 63;
    int bt = i / (24 * 64);
    float acc[8] = {0, 0, 0, 0, 0, 0, 0, 0};
    size_t base = (size_t)bt * 49152 + n * 192 + c8;
#pragma unroll
    for (int m = 0; m < 4; m++) {
        u16x8 v = *reinterpret_cast<const u16x8*>(&xp[base + m * 12288]);
#pragma unroll
        for (int e = 0; e < 8; e++) acc[e] += bf2f(v[e]);
    }
    u16x8 t;
#pragma unroll
    for (int e = 0; e < 8; e++) t[e] = f2bf(acc[e] * 0.25f);
    *reinterpret_cast<u16x8*>(&t0b[(size_t)(bt * 64 + n) * 192 + c8]) = t;
}

// ---------------------------------------------------------------------------
// MFMA bf16 GEMM:  C[row, oc] = sum_k Arow[k] * W[oc][k] + bias[oc]
// Block tile 128 rows x 96 oc, K=192 staged in 2 halves of 96. Weights bf16.
// SRC: 0 = A f32 rows (cvt); 3 = Ab bf16 row-major (pure copy);
//      4 = seq rows: g -> (bt=c0+g/320, tok); tok<64 -> Ab2(t0b) else Ab(xp2).
// EPI: 0 plain, 1 exact gelu, 2 split oc@192 (b0 len 384), 3 split (W1,b1).
// OUTBF: 0 f32 out; 1 bf16 out via LDS restage -> coalesced u16x8 stores.
// hbs: 0 = row-major [row][192] out; else head-blocked [h][row][32] with
//      h-stride = hbs elements (8-col store chunks never cross a head).
// ---------------------------------------------------------------------------
template <int SRC, int EPI, int OUTBF>
__global__ __launch_bounds__(256, 3)
void mgemm_kernel(const float* __restrict__ A, const unsigned short* __restrict__ Ab,
                  const unsigned short* __restrict__ Ab2,
                  const unsigned short* __restrict__ W0, const unsigned short* __restrict__ W1,
                  const float* __restrict__ b0, const float* __restrict__ b1,
                  void* __restrict__ C0v, void* __restrict__ C1v, int c0, int hbs)
{
    __shared__ __align__(16) char As[128 * 192];   // 24 KB bf16 [row][k(96)]
    __shared__ __align__(16) char Bs[96 * 192];    // 18 KB bf16 [oc][k(96)]
    const int tid = threadIdx.x;
    const int gm0 = blockIdx.x * 128;
    const int gn0 = blockIdx.y * 96;
    const int wid = tid >> 6;
    const int wm = wid >> 1, wn = wid & 1;
    const int lane = tid & 63;
    const int lr = lane & 15;
    const int lk = lane >> 4;

    const bool hiN = (gn0 >= 192);
    const unsigned short* Wsel = (EPI == 3 && hiN) ? W1 : W0;
    const int wrow0 = (EPI == 3 && hiN) ? (gn0 - 192) : gn0;

    f32x4 acc[4][3];
#pragma unroll
    for (int i = 0; i < 4; i++)
#pragma unroll
        for (int j = 0; j < 3; j++) acc[i][j] = (f32x4){0.f, 0.f, 0.f, 0.f};

    for (int kb = 0; kb < 192; kb += 96) {
        // ---- stage A ----
        if (SRC == 0) {
#pragma unroll
            for (int it = 0; it < 12; it++) {
                int f4 = tid + it * 256;
                int row = f4 / 24;
                int kc4 = (f4 - row * 24) * 4;
                float4 v = *reinterpret_cast<const float4*>(
                    &A[(size_t)(gm0 + row) * 192 + kb + kc4]);
                u16x4 bvv;
                bvv[0] = f2bf(v.x); bvv[1] = f2bf(v.y);
                bvv[2] = f2bf(v.z); bvv[3] = f2bf(v.w);
                int boff = (kc4 * 2) ^ ((row & 3) << 4);
                *reinterpret_cast<u16x4*>(As + row * 192 + boff) = bvv;
            }
        } else {
#pragma unroll
            for (int it = 0; it < 6; it++) {
                int f8 = tid + it * 256;
                int row = f8 / 12;
                int c16 = f8 - row * 12;
                const unsigned short* src;
                if (SRC == 3) {
                    src = &Ab[(size_t)(gm0 + row) * 192 + kb + c16 * 8];
                } else {
                    int g = gm0 + row;
                    int bt = g / 320, tok = g - bt * 320; bt += c0;
                    src = (tok < 64)
                        ? &Ab2[(size_t)(bt * 64 + tok) * 192 + kb + c16 * 8]
                        : &Ab[(size_t)bt * 49152 + ((tok >> 6) - 1) * 12288
                              + (tok & 63) * 192 + kb + c16 * 8];
                }
                u16x8 v = *reinterpret_cast<const u16x8*>(src);
                int boff = (c16 * 16) ^ ((row & 3) << 4);
                *reinterpret_cast<u16x8*>(As + row * 192 + boff) = v;
            }
        }
        // ---- stage B: 96 oc-rows x 96 k, pure bf16 copy ----
        for (int f8 = tid; f8 < 1152; f8 += 256) {
            int row = f8 / 12;
            int c16 = f8 - row * 12;
            u16x8 v = *reinterpret_cast<const u16x8*>(
                &Wsel[(size_t)(wrow0 + row) * 192 + kb + c16 * 8]);
            int boff = (c16 * 16) ^ ((row & 3) << 4);
            *reinterpret_cast<u16x8*>(Bs + row * 192 + boff) = v;
        }
        __syncthreads();

#pragma unroll
        for (int ks = 0; ks < 3; ks++) {
            s16x8 af[4], bf[3];
#pragma unroll
            for (int i = 0; i < 4; i++) {
                int row = wm * 64 + i * 16 + lr;
                int off = (ks * 64 + lk * 16) ^ ((row & 3) << 4);
                af[i] = *reinterpret_cast<const s16x8*>(As + row * 192 + off);
            }
#pragma unroll
            for (int j = 0; j < 3; j++) {
                int row = wn * 48 + j * 16 + lr;
                int off = (ks * 64 + lk * 16) ^ ((row & 3) << 4);
                bf[j] = *reinterpret_cast<const s16x8*>(Bs + row * 192 + off);
            }
#pragma unroll
            for (int i = 0; i < 4; i++)
#pragma unroll
                for (int j = 0; j < 3; j++)
                    acc[i][j] = __builtin_amdgcn_mfma_f32_16x16x32_bf16(
                        af[i], bf[j], acc[i][j], 0, 0, 0);
        }
        __syncthreads();
    }

    if (OUTBF == 0) {
#pragma unroll
        for (int j = 0; j < 3; j++) {
            int bcol = gn0 + wn * 48 + j * 16 + lr;
            float bv = (EPI == 3 && bcol >= 192) ? b1[bcol - 192] : b0[bcol];
            float* dst = (float*)C0v;
            int oc = bcol;
            if ((EPI == 2 || EPI == 3) && bcol >= 192) { dst = (float*)C1v; oc = bcol - 192; }
#pragma unroll
            for (int i = 0; i < 4; i++) {
                int rbase = gm0 + wm * 64 + i * 16 + lk * 4;
#pragma unroll
                for (int r = 0; r < 4; r++) {
                    float v = acc[i][j][r] + bv;
                    if (EPI == 1) v = 0.5f * v * (1.f + erff(v * 0.70710678118654752440f));
                    dst[(size_t)(rbase + r) * 192 + oc] = v;
                }
            }
        }
    } else {
        // bf16 out: restage via As (128*96 u16 = 24 KB), then coalesced stores
        unsigned short* As16 = (unsigned short*)As;
#pragma unroll
        for (int j = 0; j < 3; j++) {
            int bcol = gn0 + wn * 48 + j * 16 + lr;
            float bv = (EPI == 3 && bcol >= 192) ? b1[bcol - 192] : b0[bcol];
#pragma unroll
            for (int i = 0; i < 4; i++)
#pragma unroll
                for (int r = 0; r < 4; r++) {
                    float v = acc[i][j][r] + bv;
                    if (EPI == 1) v = 0.5f * v * (1.f + erff(v * 0.70710678118654752440f));
                    As16[(wm * 64 + i * 16 + lk * 4 + r) * 96 + wn * 48 + j * 16 + lr] = f2bf(v);
                }
        }
        __syncthreads();
        unsigned short* dst = (unsigned short*)((((EPI == 2) || (EPI == 3)) && hiN) ? C1v : C0v);
        const int oc0 = ((((EPI == 2) || (EPI == 3)) && hiN) ? gn0 - 192 : gn0);
#pragma unroll
        for (int it = 0; it < 6; it++) {
            int f8 = tid + it * 256;
            int row = f8 / 12, c16 = f8 - row * 12;
            u16x8 v = *reinterpret_cast<const u16x8*>(&As16[row * 96 + c16 * 8]);
            size_t idx;
            if (hbs == 0) {
                idx = (size_t)(gm0 + row) * 192 + oc0 + c16 * 8;
            } else {
                int col = oc0 + c16 * 8;          // 8-chunk stays in one head
                idx = (size_t)(col >> 5) * (size_t)hbs
                    + (size_t)(gm0 + row) * 32 + (col & 31);
            }
            *reinterpret_cast<u16x8*>(&dst[idx]) = v;
        }
    }
}

// ---------------------------------------------------------------------------
// Fused window attention, t-MERGED (r15 proven): block = (bb, m), 512 blocks,
// 768 thr = 12 waves; K/V/mask/rpbT staged F32 once, t=0..3 looped inside.
// VGPR 84, zero spill. Epilogue adds pos before bf16 rounding.
// ---------------------------------------------------------------------------
__global__ __launch_bounds__(768, 1)
void winattn_kernel(const float* __restrict__ qbuf,
                    const unsigned short* __restrict__ kbuf,
                    const unsigned short* __restrict__ vbuf,
                    const float* __restrict__ mask,
                    const float* __restrict__ rpbt, const float* __restrict__ pos,
                    unsigned short* __restrict__ xp)
{
    __shared__ float klds[64 * 192];       // 48 KB
    __shared__ float vlds[64 * 192];       // 48 KB
    __shared__ float mlds[64 * 65];        // 16.25 KB
    __shared__ float rldsT[6 * 225];       // 5.3 KB  [h][ridx]
    __shared__ float exm[768];
    __shared__ float exl[768];
    __shared__ unsigned obuf[6 * 64 * 17]; // 25.5 KB
    const int tid = threadIdx.x;
    const int bid = blockIdx.x;            // bb*4 + m
    const int bb = bid >> 2;
    const int m = bid & 3;
    const int w = tid >> 6;
    const int h = w >> 1;
    const int lane = tid & 63;

    const int kvbase = (bb * 4 + m) * 12288;
#pragma unroll
    for (int it = 0; it < 2; it++) {
        int i8 = tid + it * 768;
        u16x8 kq = *reinterpret_cast<const u16x8*>(&kbuf[kvbase + i8 * 8]);
        u16x8 vq = *reinterpret_cast<const u16x8*>(&vbuf[kvbase + i8 * 8]);
        f32x4 k0, k1, v0, v1;
#pragma unroll
        for (int e = 0; e < 4; e++) {
            k0[e] = bf2f(kq[e]); k1[e] = bf2f(kq[e + 4]);
            v0[e] = bf2f(vq[e]); v1[e] = bf2f(vq[e + 4]);
        }
        *reinterpret_cast<f32x4*>(&klds[i8 * 8]) = k0;
        *reinterpret_cast<f32x4*>(&klds[i8 * 8 + 4]) = k1;
        *reinterpret_cast<f32x4*>(&vlds[i8 * 8]) = v0;
        *reinterpret_cast<f32x4*>(&vlds[i8 * 8 + 4]) = v1;
    }
    const int widx = bb & 63;
    for (int f = tid; f < 4096; f += 768)
        mlds[(f >> 6) * 65 + (f & 63)] = mask[widx * 4096 + f];
    for (int f = tid; f < 1350; f += 768) {
        int hh = f / 225, rr = f - hh * 225;
        rldsT[f] = rpbt[rr * 6 + hh];
    }
    __syncthreads();

    const float scale = 0.17677669529663688110f;  // 1/sqrt(32)
    const int ni = lane >> 3, nj = lane & 7;
    const int e0 = (w & 1) << 5;

    for (int t = 0; t < 4; t++) {
        float qreg[32];
        const int qbase = ((bb * 4 + t) * 64 + lane) * 192 + h * 32;
#pragma unroll
        for (int j = 0; j < 8; j++) {
            float4 v = *reinterpret_cast<const float4*>(&qbuf[qbase + j * 4]);
            qreg[4 * j] = v.x; qreg[4 * j + 1] = v.y;
            qreg[4 * j + 2] = v.z; qreg[4 * j + 3] = v.w;
        }
        float s[32];
#pragma unroll
        for (int ee = 0; ee < 32; ee++) {
            int e = e0 + ee;
            const float4* kr = reinterpret_cast<const float4*>(&klds[e * 192 + h * 32]);
            float d0 = 0, d1 = 0, d2 = 0, d3 = 0;
#pragma unroll
            for (int q8 = 0; q8 < 8; q8++) {
                float4 k4 = kr[q8];
                d0 += qreg[q8 * 4] * k4.x;
                d1 += qreg[q8 * 4 + 1] * k4.y;
                d2 += qreg[q8 * 4 + 2] * k4.z;
                d3 += qreg[q8 * 4 + 3] * k4.w;
            }
            int ridx = (ni - (e >> 3) + 7) * 15 + (nj - (e & 7) + 7);
            s[ee] = (d0 + d1 + d2 + d3) * scale + rldsT[h * 225 + ridx] + mlds[lane * 65 + e];
        }
        float mrun = s[0];
#pragma unroll
        for (int ee = 1; ee < 32; ee++) mrun = fmaxf(mrun, s[ee]);
        float lrun = 0.f;
#pragma unroll
        for (int ee = 0; ee < 32; ee++) { s[ee] = __expf(s[ee] - mrun); lrun += s[ee]; }

        float o[32];
#pragma unroll
        for (int d = 0; d < 32; d++) o[d] = 0.f;
#pragma unroll
        for (int ee = 0; ee < 32; ee++) {
            float p = s[ee];
            const float4* vr = reinterpret_cast<const float4*>(&vlds[(e0 + ee) * 192 + h * 32]);
#pragma unroll
            for (int d8 = 0; d8 < 8; d8++) {
                float4 v4 = vr[d8];
                o[d8 * 4] += p * v4.x; o[d8 * 4 + 1] += p * v4.y;
                o[d8 * 4 + 2] += p * v4.z; o[d8 * 4 + 3] += p * v4.w;
            }
        }

        __syncthreads();                   // B1: prior t's obuf/exl reads done
        exm[w * 64 + lane] = mrun;
        __syncthreads();                   // B2
        float mo = exm[(w ^ 1) * 64 + lane];
        float mt = fmaxf(mrun, mo);
        float fs = __expf(mrun - mt);
        if (w & 1) {
            unsigned* ob = &obuf[h * 1088 + lane * 17];
#pragma unroll
            for (int j = 0; j < 16; j++) {
                unsigned lo = f2bf(fs * o[2 * j]);
                unsigned hi = f2bf(fs * o[2 * j + 1]);
                ob[j] = lo | (hi << 16);
            }
            exl[w * 64 + lane] = fs * lrun;
        }
        __syncthreads();                   // B3
        if (!(w & 1)) {
            float lt = fs * lrun + exl[(w + 1) * 64 + lane];
            const float inv = 1.f / lt;
            const unsigned* ob = &obuf[h * 1088 + lane * 17];
            const int obase = bb * 196608 + m * 49152 + t * 12288 + h * 2048 + lane * 32;
#pragma unroll
            for (int j = 0; j < 8; j++) {
                unsigned p0 = ob[2 * j], p1 = ob[2 * j + 1];
                float4 pv = *reinterpret_cast<const float4*>(&pos[h * 2048 + lane * 32 + j * 4]);
                u16x4 v;
                v[0] = f2bf((fs * o[4 * j]     + bf2f((unsigned short)(p0 & 0xffff))) * inv + pv.x);
                v[1] = f2bf((fs * o[4 * j + 1] + bf2f((unsigned short)(p0 >> 16))) * inv + pv.y);
                v[2] = f2bf((fs * o[4 * j + 2] + bf2f((unsigned short)(p1 & 0xffff))) * inv + pv.z);
                v[3] = f2bf((fs * o[4 * j + 3] + bf2f((unsigned short)(p1 >> 16))) * inv + pv.w);
                *reinterpret_cast<u16x4*>(&xp[obase + j * 4]) = v;
            }
        }
    }
}

// ---------------------------------------------------------------------------
// Pooling attention (r16 proven): block = (h, btl), 320 thr = 5 waves; wave w
// handles key tiles {w, w+5} of 10 (32 keys). kk/vv HEAD-BLOCKED [h][tok][32]
// (h-stride hbs) -> staging is one contiguous 2 KB u16x8 stream per tile.
// qreg reloaded per key-tile iteration (#pragma unroll 1): cross-phase live
// ~40 regs, no spill. Final merge parallelized across 4 waves (8 dims each).
// ---------------------------------------------------------------------------
__global__ __launch_bounds__(320)
void poolattn3_kernel(const unsigned short* __restrict__ kk,
                      const unsigned short* __restrict__ vv,
                      const float* __restrict__ qq,
                      unsigned short* __restrict__ opool, int c0, int hbs)
{
    __shared__ float ubuf[10560];
    __shared__ float scm[320], scl[320];
    const int tid = threadIdx.x;
    const int w = tid >> 6, lane = tid & 63;
    const int h = blockIdx.x, btl = blockIdx.y;
    const int bt = c0 + btl;
    float* Kf = ubuf + w * 2048;
    float* Vf = Kf + 1024;

    const float scale = 0.17677669529663688110f;
    float mrun = -3.0e38f, lrun = 0.f;
    float o[32];
#pragma unroll
    for (int d = 0; d < 32; d++) o[d] = 0.f;

    const size_t qbase = (size_t)(bt * 64 + lane) * 192 + h * 32;
    const size_t hb = (size_t)h * hbs;

#pragma unroll 1
    for (int it = 0; it < 2; it++) {
        const int tt = w + it * 5;
        const unsigned short* ks = kk + hb + ((size_t)btl * 320 + tt * 32) * 32;
        const unsigned short* vs = vv + hb + ((size_t)btl * 320 + tt * 32) * 32;
#pragma unroll
        for (int ci = 0; ci < 2; ci++) {
            int i8 = lane + ci * 64;           // 0..127
            u16x8 kv8 = *reinterpret_cast<const u16x8*>(&ks[i8 * 8]);
            u16x8 vv8 = *reinterpret_cast<const u16x8*>(&vs[i8 * 8]);
            f32x4 lo, hi, vlo, vhi;
#pragma unroll
            for (int e = 0; e < 4; e++) {
                lo[e] = bf2f(kv8[e]);  hi[e] = bf2f(kv8[e + 4]);
                vlo[e] = bf2f(vv8[e]); vhi[e] = bf2f(vv8[e + 4]);
            }
            *reinterpret_cast<f32x4*>(Kf + i8 * 8) = lo;
            *reinterpret_cast<f32x4*>(Kf + i8 * 8 + 4) = hi;
            *reinterpret_cast<f32x4*>(Vf + i8 * 8) = vlo;
            *reinterpret_cast<f32x4*>(Vf + i8 * 8 + 4) = vhi;
        }
        float qreg[32];
#pragma unroll
        for (int j = 0; j < 8; j++) {
            float4 v = *reinterpret_cast<const float4*>(&qq[qbase + j * 4]);
            qreg[4 * j] = v.x; qreg[4 * j + 1] = v.y;
            qreg[4 * j + 2] = v.z; qreg[4 * j + 3] = v.w;
        }
        float s[32];
#pragma unroll
        for (int j = 0; j < 32; j++) {
            const float4* kr = reinterpret_cast<const float4*>(Kf + j * 32);
            float d0 = 0, d1 = 0, d2 = 0, d3 = 0;
#pragma unroll
            for (int q8 = 0; q8 < 8; q8++) {
                float4 k4 = kr[q8];
                d0 += qreg[q8 * 4] * k4.x;
                d1 += qreg[q8 * 4 + 1] * k4.y;
                d2 += qreg[q8 * 4 + 2] * k4.z;
                d3 += qreg[q8 * 4 + 3] * k4.w;
            }
            s[j] = (d0 + d1 + d2 + d3) * scale;
        }
        float mt = s[0];
#pragma unroll
        for (int j = 1; j < 32; j++) mt = fmaxf(mt, s[j]);
        float mnew = fmaxf(mrun, mt);
        float fct = __expf(mrun - mnew);
        lrun *= fct;
#pragma unroll
        for (int d = 0; d < 32; d++) o[d] *= fct;
#pragma unroll
        for (int j = 0; j < 32; j++) { float p = __expf(s[j] - mnew); lrun += p; s[j] = p; }
#pragma unroll
        for (int j = 0; j < 32; j++) {
            float p = s[j];
            const float4* vr = reinterpret_cast<const float4*>(Vf + j * 32);
#pragma unroll
            for (int d8 = 0; d8 < 8; d8++) {
                float4 v4 = vr[d8];
                o[d8 * 4] += p * v4.x; o[d8 * 4 + 1] += p * v4.y;
                o[d8 * 4 + 2] += p * v4.z; o[d8 * 4 + 3] += p * v4.w;
            }
        }
        mrun = mnew;
    }
    __syncthreads();
    scm[w * 64 + lane] = mrun;
    scl[w * 64 + lane] = lrun;
#pragma unroll
    for (int d = 0; d < 32; d++) ubuf[w * 2112 + lane * 33 + d] = o[d];
    __syncthreads();

    if (tid < 256) {                 // 4-wave merge: q = tid&63, 8 dims each
        const int q = tid & 63, grp = tid >> 6;
        float m5 = scm[q];
#pragma unroll
        for (int ww = 1; ww < 5; ww++) m5 = fmaxf(m5, scm[ww * 64 + q]);
        float den = 0.f;
        float od[8];
#pragma unroll
        for (int e = 0; e < 8; e++) od[e] = 0.f;
#pragma unroll
        for (int ww = 0; ww < 5; ww++) {
            float f = __expf(scm[ww * 64 + q] - m5);
            den += f * scl[ww * 64 + q];
            const float* src = ubuf + ww * 2112 + q * 33 + grp * 8;
#pragma unroll
            for (int e = 0; e < 8; e++) od[e] += f * src[e];
        }
        const float inv = 1.f / den;
        const size_t ob = (size_t)(bt * 64 + q) * 192 + h * 32 + grp * 8;
        u16x4 v0, v1;
#pragma unroll
        for (int e = 0; e < 4; e++) { v0[e] = f2bf(od[e] * inv); v1[e] = f2bf(od[e + 4] * inv); }
        *reinterpret_cast<u16x4*>(&opool[ob]) = v0;
        *reinterpret_cast<u16x4*>(&opool[ob + 4]) = v1;
    }
}

extern "C" void kernel_launch(void* const* d_in, const int* in_sizes, int n_in,
                              void* d_out, int out_size, void* d_ws, size_t ws_size,
                              hipStream_t stream) {
    (void)in_sizes; (void)n_in; (void)out_size; (void)ws_size;
    const float* x      = (const float*)d_in[0];
    const float* x_kv   = (const float*)d_in[1];
    const float* mask   = (const float*)d_in[2];
    const float* rpbt   = (const float*)d_in[3];
    const float* q_w    = (const float*)d_in[4];
    const float* q_b    = (const float*)d_in[5];
    const float* kv_w   = (const float*)d_in[6];
    const float* kv_b   = (const float*)d_in[7];
    const float* pos    = (const float*)d_in[8];
    const float* pq_w   = (const float*)d_in[9];
    const float* pq_b   = (const float*)d_in[10];
    const float* pk_w   = (const float*)d_in[11];
    const float* pk_b   = (const float*)d_in[12];
    const float* pv_w   = (const float*)d_in[13];
    const float* pv_b   = (const float*)d_in[14];
    const float* po_w   = (const float*)d_in[15];
    const float* po_b   = (const float*)d_in[16];
    const float* proj_w = (const float*)d_in[17];
    const float* proj_b = (const float*)d_in[18];
    float* out = (float*)d_out;
    char* ws = (char*)d_ws;

    float*          qbuf   = (float*)(ws);                        // 24 MB
    unsigned short* xp     = (unsigned short*)(ws + 25165824u);   // 48 MB
    unsigned short* kbuf   = (unsigned short*)(ws + 75497472u);   // 12 MB
    unsigned short* vbuf   = (unsigned short*)(ws + 88080384u);   // 12 MB
    unsigned short* kkc    = (unsigned short*)(ws + 75497472u);   // 30 MB/chunk
    unsigned short* vvc    = (unsigned short*)(ws + 106954752u);  // 30 MB/chunk
    unsigned short* t0b    = (unsigned short*)(ws + 138412032u);  // 12.6 MB
    unsigned short* opoolb = (unsigned short*)(ws + 150994944u);  // 12.6 MB
    unsigned short* opob   = (unsigned short*)(ws + 163577856u);  // 12.6 MB
    unsigned short* wbf    = (unsigned short*)(ws + 176160768u);  // 0.59 MB
    float*          qq     = qbuf;
    const int HBS = 256 * 320 * 32;   // head-block stride (elements) per chunk

    dim3 blk(256);
    wcvt_kernel<<<1152, blk, 0, stream>>>(q_w, kv_w, pq_w, pk_w, pv_w, po_w, proj_w, wbf);
    // q = x @ q_w^T + q_b  (f32 A path)
    mgemm_kernel<0, 0, 0><<<dim3(256, 2), blk, 0, stream>>>(
        x, nullptr, nullptr, wbf, nullptr, q_b, nullptr, qbuf, nullptr, 0, 0);
    // k,v = x_kv @ kv_w^T + kv_b  (split, bf16 out, row-major)
    mgemm_kernel<0, 2, 1><<<dim3(256, 4), blk, 0, stream>>>(
        x_kv, nullptr, nullptr, wbf + 36864, nullptr, kv_b, nullptr, kbuf, vbuf, 0, 0);
    // window attention, t-merged; writes xp2 = attn_out + pos
    winattn_kernel<<<512, 768, 0, stream>>>(qbuf, kbuf, vbuf, mask, rpbt, pos, xp);
    // t0 = mean_m(xp2)
    prep_kernel<<<3072, blk, 0, stream>>>(xp, t0b);
    // qq = t0 @ pq_w^T + pq_b
    mgemm_kernel<3, 0, 0><<<dim3(256, 2), blk, 0, stream>>>(
        nullptr, t0b, nullptr, wbf + 110592, nullptr, pq_b, nullptr, qq, nullptr, 0, 0);
    // pooling in 2 chunks of 256 bt (kk/vv head-blocked)
    for (int c0 = 0; c0 < 512; c0 += 256) {
        mgemm_kernel<4, 3, 1><<<dim3(640, 4), blk, 0, stream>>>(
            nullptr, xp, t0b, wbf + 147456, wbf + 184320, pk_b, pv_b, kkc, vvc, c0, HBS);
        poolattn3_kernel<<<dim3(6, 256), 320, 0, stream>>>(kkc, vvc, qq, opoolb, c0, HBS);
    }
    // opo = gelu(opool @ po_w^T + po_b)  (bf16 in/out)
    mgemm_kernel<3, 1, 1><<<dim3(256, 2), blk, 0, stream>>>(
        nullptr, opoolb, nullptr, wbf + 221184, nullptr, po_b, nullptr, opob, nullptr, 0, 0);
    // out = opo @ proj_w^T + proj_b  (f32 out)
    mgemm_kernel<3, 0, 0><<<dim3(256, 2), blk, 0, stream>>>(
        nullptr, opob, nullptr, wbf + 258048, nullptr, proj_b, nullptr, out, nullptr, 0, 0);
}